// Round 4
// baseline (135.453 us; speedup 1.0000x reference)
//
#include <hip/hip_runtime.h>

// out[b,i,j] = sum_f input[b,i,j,f] * theta[i,j,f]
// B=64, L=200, F=64.  input: [B, L*L, F] fp32, theta: [L*L, F] fp32,
// out: [B, L*L] fp32.
//
// Strategy (round 4): identical to round 3 EXCEPT the outer batch loop is
// NOT fully unrolled (#pragma unroll 1). Full unroll (16 iters x 4 loads)
// hoists ~64 addresses + clusters loads -> VGPR blowup -> occupancy drop /
// spills, hurting the latency-hiding this streaming kernel lives on.
//  - theta fragment in registers for the whole kernel (HBM-read once).
//  - 4 independent non-temporal 16B loads in flight per thread per iter.
//  - Each load instruction covers 1KB contiguous per wave (coalesced).
//  - 4-step __shfl_xor reduce within each 16-lane group.

#define BQ 64          // batch
#define LQ 200
#define FQ 64
#define IJ (LQ * LQ)   // 40000
#define EPB 16         // output elements per block (256 threads / 16 lanes)
#define CHUNKS (IJ / EPB)  // 2500

typedef float f32x4 __attribute__((ext_vector_type(4)));

__global__ __launch_bounds__(256)
void IRLLinearModel_42786464203479_kernel(const float* __restrict__ inp,
                                          const float* __restrict__ theta,
                                          float* __restrict__ out) {
    const int chunk = blockIdx.x;

    const int g = threadIdx.x >> 4;   // element-within-chunk: 0..15
    const int s = threadIdx.x & 15;   // lane-within-group:    0..15

    const int ij = chunk * EPB + g;   // 2500*16 == 40000 exactly

    // theta fragment: registers for the whole kernel (read once)
    const f32x4 t = *reinterpret_cast<const f32x4*>(theta + (size_t)ij * FQ + (size_t)s * 4);

    const float* in_base = inp + (size_t)ij * FQ + (size_t)s * 4;
    const size_t bstride = (size_t)IJ * FQ;   // elements between batches

    float* out_base = out + ij;

    #pragma unroll 1
    for (int b0 = 0; b0 < BQ; b0 += 4) {
        // 4 independent non-temporal loads in flight
        const f32x4 a0 = __builtin_nontemporal_load(
            reinterpret_cast<const f32x4*>(in_base + (size_t)(b0 + 0) * bstride));
        const f32x4 a1 = __builtin_nontemporal_load(
            reinterpret_cast<const f32x4*>(in_base + (size_t)(b0 + 1) * bstride));
        const f32x4 a2 = __builtin_nontemporal_load(
            reinterpret_cast<const f32x4*>(in_base + (size_t)(b0 + 2) * bstride));
        const f32x4 a3 = __builtin_nontemporal_load(
            reinterpret_cast<const f32x4*>(in_base + (size_t)(b0 + 3) * bstride));

        float p0 = a0.x * t.x + a0.y * t.y + a0.z * t.z + a0.w * t.w;
        float p1 = a1.x * t.x + a1.y * t.y + a1.z * t.z + a1.w * t.w;
        float p2 = a2.x * t.x + a2.y * t.y + a2.z * t.z + a2.w * t.w;
        float p3 = a3.x * t.x + a3.y * t.y + a3.z * t.z + a3.w * t.w;

        // reduce across the 16-lane group (masks < 16 stay inside the group)
        p0 += __shfl_xor(p0, 1);  p1 += __shfl_xor(p1, 1);
        p2 += __shfl_xor(p2, 1);  p3 += __shfl_xor(p3, 1);
        p0 += __shfl_xor(p0, 2);  p1 += __shfl_xor(p1, 2);
        p2 += __shfl_xor(p2, 2);  p3 += __shfl_xor(p3, 2);
        p0 += __shfl_xor(p0, 4);  p1 += __shfl_xor(p1, 4);
        p2 += __shfl_xor(p2, 4);  p3 += __shfl_xor(p3, 4);
        p0 += __shfl_xor(p0, 8);  p1 += __shfl_xor(p1, 8);
        p2 += __shfl_xor(p2, 8);  p3 += __shfl_xor(p3, 8);

        if (s == 0) {
            __builtin_nontemporal_store(p0, out_base + (size_t)(b0 + 0) * IJ);
            __builtin_nontemporal_store(p1, out_base + (size_t)(b0 + 1) * IJ);
            __builtin_nontemporal_store(p2, out_base + (size_t)(b0 + 2) * IJ);
            __builtin_nontemporal_store(p3, out_base + (size_t)(b0 + 3) * IJ);
        }
    }
}

extern "C" void kernel_launch(void* const* d_in, const int* in_sizes, int n_in,
                              void* d_out, int out_size, void* d_ws, size_t ws_size,
                              hipStream_t stream) {
    const float* inp   = (const float*)d_in[0];
    const float* theta = (const float*)d_in[1];
    float* out = (float*)d_out;

    IRLLinearModel_42786464203479_kernel<<<CHUNKS, 256, 0, stream>>>(inp, theta, out);
}